// Round 1
// baseline (608.676 us; speedup 1.0000x reference)
//
#include <hip/hip_runtime.h>

#define NB 8
#define NS 2048
#define ND 512
#define QB 32
#define KB 64

#define QP 520   // Q LDS pitch (bf16): 512 + 8
#define KP 136   // K d-chunk pitch: 128 + 8
#define VP 72    // V^T tile pitch: 64 + 8
#define PP 72    // P tile pitch: 64 + 8

// LDS layout (bytes)
#define QS_OFF   0
#define KS_OFF   33280                  // 32*520*2
#define VTS_OFF  50688                  // + 64*136*2
#define PS_OFF   124416                 // + 512*72*2
#define MROW_OFF 129024                 // + 32*72*2
#define AROW_OFF 129152
#define LROW_OFF 129280
#define TMAX_OFF 129408
#define TSUM_OFF 129920
#define LDS_BYTES 130432

typedef __attribute__((ext_vector_type(4))) float f32x4;
typedef __attribute__((ext_vector_type(8))) short s16x8;

__device__ __forceinline__ unsigned short f2bf(float f) {
    unsigned int u = __float_as_uint(f);
    u += 0x7FFF + ((u >> 16) & 1);   // round-to-nearest-even
    return (unsigned short)(u >> 16);
}

// ---- pre-pass: Q,K fp32 -> bf16 (Q pre-scaled by 1/sqrt(D)) ----
__global__ void cvt_qk_kernel(const float* __restrict__ Q, const float* __restrict__ K,
                              unsigned short* __restrict__ Qb, unsigned short* __restrict__ Kb) {
    const float scale = 0.04419417382415922f;  // 1/sqrt(512)
    size_t i = ((size_t)blockIdx.x * 256 + threadIdx.x) * 4;
    float4 q = *(const float4*)(Q + i);
    float4 k = *(const float4*)(K + i);
    ushort4 qo, ko;
    qo.x = f2bf(q.x * scale); qo.y = f2bf(q.y * scale);
    qo.z = f2bf(q.z * scale); qo.w = f2bf(q.w * scale);
    ko.x = f2bf(k.x); ko.y = f2bf(k.y); ko.z = f2bf(k.z); ko.w = f2bf(k.w);
    *(ushort4*)(Qb + i) = qo;
    *(ushort4*)(Kb + i) = ko;
}

// ---- pre-pass: V fp32 [b][s][d] -> V^T bf16 [b][d][s] ----
__global__ void cvt_vt_kernel(const float* __restrict__ V, unsigned short* __restrict__ Vt) {
    __shared__ float tile[32][33];
    int bid = blockIdx.x;
    int dt = bid & 15;          // D/32 = 16
    int st = (bid >> 4) & 63;   // S/32 = 64
    int b  = bid >> 10;
    int t = threadIdx.x;
    int sl = t >> 3, dq = t & 7;
    const float* src = V + ((size_t)b * NS + st * 32 + sl) * ND + dt * 32 + dq * 4;
    float4 v = *(const float4*)src;
    tile[sl][dq * 4 + 0] = v.x; tile[sl][dq * 4 + 1] = v.y;
    tile[sl][dq * 4 + 2] = v.z; tile[sl][dq * 4 + 3] = v.w;
    __syncthreads();
    int dl = t >> 3, sq = t & 7;
    ushort4 o;
    o.x = f2bf(tile[sq * 4 + 0][dl]);
    o.y = f2bf(tile[sq * 4 + 1][dl]);
    o.z = f2bf(tile[sq * 4 + 2][dl]);
    o.w = f2bf(tile[sq * 4 + 3][dl]);
    *(ushort4*)(Vt + ((size_t)b * ND + dt * 32 + dl) * NS + st * 32 + sq * 4) = o;
}

// ---- main flash-attention kernel ----
// grid: NB * (NS/QB) blocks; 256 threads (4 waves).
// b = blockIdx&7 (batch<->XCD affinity), qt = blockIdx>>3.
// QK^T: wave w owns k-cols [w*16, w*16+16) of the KB=64 tile.
// PV:   wave w owns output d-cols [w*128, w*128+128).
__global__ void __launch_bounds__(256) attn_kernel(const unsigned short* __restrict__ Qg_,
                                                   const unsigned short* __restrict__ Kg_,
                                                   const unsigned short* __restrict__ Vg_,
                                                   float* __restrict__ out) {
    extern __shared__ __align__(16) char smem[];
    unsigned short* Qs  = (unsigned short*)(smem + QS_OFF);   // [32][QP]
    unsigned short* Ks  = (unsigned short*)(smem + KS_OFF);   // [64][KP]
    unsigned short* Vts = (unsigned short*)(smem + VTS_OFF);  // [512][VP]
    unsigned short* Ps  = (unsigned short*)(smem + PS_OFF);   // [32][PP]
    float* mrow = (float*)(smem + MROW_OFF);                  // [32]
    float* arow = (float*)(smem + AROW_OFF);                  // [32]
    float* lrow = (float*)(smem + LROW_OFF);                  // [32]
    float* tmax = (float*)(smem + TMAX_OFF);                  // [4][32]
    float* tsum = (float*)(smem + TSUM_OFF);                  // [4][32]

    const int tid  = threadIdx.x;
    const int lane = tid & 63;
    const int w    = tid >> 6;
    const int g    = lane >> 4;    // 0..3
    const int c    = lane & 15;    // 0..15
    const int b    = blockIdx.x & 7;
    const int qt   = blockIdx.x >> 3;

    const unsigned short* Qg = Qg_ + ((size_t)b * NS + qt * QB) * ND;
    const unsigned short* Kg = Kg_ + (size_t)b * NS * ND;
    const unsigned short* Vg = Vg_ + (size_t)b * ND * NS;   // [512][2048]

    // stage Q tile (32 x 512 bf16), rows contiguous in global
    #pragma unroll
    for (int it = 0; it < 8; ++it) {
        int idx = it * 2048 + tid * 8;
        int r = idx >> 9, cc = idx & 511;
        *(s16x8*)(Qs + r * QP + cc) = *(const s16x8*)(Qg + idx);
    }
    if (tid < 32) { mrow[tid] = -INFINITY; lrow[tid] = 0.f; }

    f32x4 o[2][8];
    #pragma unroll
    for (int i = 0; i < 2; ++i)
        for (int j = 0; j < 8; ++j) o[i][j] = (f32x4){0.f, 0.f, 0.f, 0.f};

    for (int kt = 0; kt < NS / KB; ++kt) {
        // ---- QK^T: accumulate 32q x 16k per wave over 4 d-chunks of 128 ----
        f32x4 sc[2] = {(f32x4){0.f,0.f,0.f,0.f}, (f32x4){0.f,0.f,0.f,0.f}};
        for (int dc = 0; dc < 4; ++dc) {
            __syncthreads();   // also guards Ks/Ps/Vts from previous iter's readers
            #pragma unroll
            for (int it = 0; it < 4; ++it) {
                int idx = it * 2048 + tid * 8;
                int r = idx >> 7, cc = idx & 127;
                *(s16x8*)(Ks + r * KP + cc) =
                    *(const s16x8*)(Kg + (size_t)(kt * KB + r) * ND + dc * 128 + cc);
            }
            __syncthreads();
            #pragma unroll
            for (int ds = 0; ds < 4; ++ds) {
                s16x8 bk = *(const s16x8*)(Ks + (w * 16 + c) * KP + ds * 32 + g * 8);
                #pragma unroll
                for (int qb = 0; qb < 2; ++qb) {
                    s16x8 aq = *(const s16x8*)(Qs + (qb * 16 + c) * QP + dc * 128 + ds * 32 + g * 8);
                    sc[qb] = __builtin_amdgcn_mfma_f32_16x16x32_bf16(aq, bk, sc[qb], 0, 0, 0);
                }
            }
        }

        // ---- online softmax ----
        // local row-max across this wave's 16 k-cols (cols live in lanes c=0..15)
        f32x4 rm[2] = {sc[0], sc[1]};
        #pragma unroll
        for (int off = 1; off < 16; off <<= 1)
            #pragma unroll
            for (int qb = 0; qb < 2; ++qb)
                for (int r = 0; r < 4; ++r)
                    rm[qb][r] = fmaxf(rm[qb][r], __shfl_xor(rm[qb][r], off));
        if (c == 0)
            #pragma unroll
            for (int qb = 0; qb < 2; ++qb)
                for (int r = 0; r < 4; ++r)
                    tmax[w * 32 + qb * 16 + g * 4 + r] = rm[qb][r];
        __syncthreads();
        if (tid < 32) {
            float mo = mrow[tid];
            float mn = fmaxf(fmaxf(tmax[tid], tmax[32 + tid]), fmaxf(tmax[64 + tid], tmax[96 + tid]));
            mn = fmaxf(mo, mn);
            mrow[tid] = mn;
            arow[tid] = __expf(mo - mn);   // 0 on first tile (mo = -inf)
        }
        __syncthreads();

        float mn8[2][4], a8[2][4];
        #pragma unroll
        for (int qb = 0; qb < 2; ++qb)
            for (int r = 0; r < 4; ++r) {
                int row = qb * 16 + g * 4 + r;
                mn8[qb][r] = mrow[row];
                a8[qb][r]  = arow[row];
            }
        f32x4 p[2];
        #pragma unroll
        for (int qb = 0; qb < 2; ++qb)
            for (int r = 0; r < 4; ++r)
                p[qb][r] = __expf(sc[qb][r] - mn8[qb][r]);
        // rescale O by alpha
        #pragma unroll
        for (int qb = 0; qb < 2; ++qb)
            for (int nb = 0; nb < 8; ++nb)
                for (int r = 0; r < 4; ++r)
                    o[qb][nb][r] *= a8[qb][r];
        // local row-sum of P
        f32x4 rs[2] = {p[0], p[1]};
        #pragma unroll
        for (int off = 1; off < 16; off <<= 1)
            #pragma unroll
            for (int qb = 0; qb < 2; ++qb)
                for (int r = 0; r < 4; ++r)
                    rs[qb][r] += __shfl_xor(rs[qb][r], off);
        if (c == 0)
            #pragma unroll
            for (int qb = 0; qb < 2; ++qb)
                for (int r = 0; r < 4; ++r)
                    tsum[w * 32 + qb * 16 + g * 4 + r] = rs[qb][r];
        // write P (bf16) to LDS: row = q, col = k within tile
        #pragma unroll
        for (int qb = 0; qb < 2; ++qb)
            for (int r = 0; r < 4; ++r)
                Ps[(qb * 16 + g * 4 + r) * PP + w * 16 + c] = f2bf(p[qb][r]);

        // ---- stage V^T tile (512 d-rows x 64 k-cols) ----
        #pragma unroll
        for (int it = 0; it < 16; ++it) {
            int idx = it * 2048 + tid * 8;
            int n = idx >> 6, kk = idx & 63;
            *(s16x8*)(Vts + n * VP + kk) = *(const s16x8*)(Vg + (size_t)n * NS + kt * KB + kk);
        }
        __syncthreads();
        if (tid < 32)
            lrow[tid] = lrow[tid] * arow[tid] +
                        (tsum[tid] + tsum[32 + tid] + tsum[64 + tid] + tsum[96 + tid]);

        // ---- PV: O[32 x 128(w)] += P(32x64) @ V(64x128) ----
        #pragma unroll
        for (int ks = 0; ks < 2; ++ks) {
            s16x8 ap0 = *(const s16x8*)(Ps + c * PP + ks * 32 + g * 8);
            s16x8 ap1 = *(const s16x8*)(Ps + (16 + c) * PP + ks * 32 + g * 8);
            #pragma unroll
            for (int nb = 0; nb < 8; ++nb) {
                s16x8 bv = *(const s16x8*)(Vts + (w * 128 + nb * 16 + c) * VP + ks * 32 + g * 8);
                o[0][nb] = __builtin_amdgcn_mfma_f32_16x16x32_bf16(ap0, bv, o[0][nb], 0, 0, 0);
                o[1][nb] = __builtin_amdgcn_mfma_f32_16x16x32_bf16(ap1, bv, o[1][nb], 0, 0, 0);
            }
        }
    }

    __syncthreads();
    float li[2][4];
    #pragma unroll
    for (int qb = 0; qb < 2; ++qb)
        for (int r = 0; r < 4; ++r)
            li[qb][r] = 1.f / lrow[qb * 16 + g * 4 + r];
    float* Og = out + ((size_t)b * NS + qt * QB) * ND;
    #pragma unroll
    for (int qb = 0; qb < 2; ++qb)
        for (int nb = 0; nb < 8; ++nb)
            for (int r = 0; r < 4; ++r)
                Og[(size_t)(qb * 16 + g * 4 + r) * ND + w * 128 + nb * 16 + c] =
                    o[qb][nb][r] * li[qb][r];
}

extern "C" void kernel_launch(void* const* d_in, const int* in_sizes, int n_in,
                              void* d_out, int out_size, void* d_ws, size_t ws_size,
                              hipStream_t stream) {
    const float* V = (const float*)d_in[0];
    const float* K = (const float*)d_in[1];
    const float* Q = (const float*)d_in[2];
    float* out = (float*)d_out;

    unsigned short* Qb = (unsigned short*)d_ws;
    unsigned short* Kb = Qb + (size_t)NB * NS * ND;
    unsigned short* Vt = Kb + (size_t)NB * NS * ND;

    hipFuncSetAttribute(reinterpret_cast<const void*>(attn_kernel),
                        hipFuncAttributeMaxDynamicSharedMemorySize, LDS_BYTES);

    // 8 batches * 2048 * 512 / (256 threads * 4 elems) = 8192 blocks
    cvt_qk_kernel<<<8192, 256, 0, stream>>>(Q, K, Qb, Kb);
    cvt_vt_kernel<<<8192, 256, 0, stream>>>(V, Vt);
    attn_kernel<<<NB * (NS / QB), 256, LDS_BYTES, stream>>>(Qb, Kb, Vt, out);
}

// Round 2
// 268.885 us; speedup vs baseline: 2.2637x; 2.2637x over previous
//
#include <hip/hip_runtime.h>

#define NB 8
#define NS 2048
#define ND 512
#define QB 32
#define KB 128

#define QP 520   // Q LDS pitch (bf16): 512 + 8
#define PP 136   // P tile pitch: 128 + 8

// LDS layout (bytes)
#define QS_OFF   0                    // 32*520*2 = 33280
#define PS_OFF   33280                // 32*136*2 = 8704
#define MROW_OFF 41984                // 32*4
#define AROW_OFF 42112
#define LROW_OFF 42240
#define TMAX_OFF 42368                // 8*32*4 = 1024
#define TSUM_OFF 43392                // 1024
#define LDS_BYTES 44416

typedef __attribute__((ext_vector_type(4))) float f32x4;
typedef __attribute__((ext_vector_type(8))) short s16x8;

__device__ __forceinline__ unsigned short f2bf(float f) {
    unsigned int u = __float_as_uint(f);
    u += 0x7FFF + ((u >> 16) & 1);   // round-to-nearest-even
    return (unsigned short)(u >> 16);
}

// ---- pre-pass: Q,K fp32 -> bf16 (Q pre-scaled by 1/sqrt(D)) ----
__global__ void cvt_qk_kernel(const float* __restrict__ Q, const float* __restrict__ K,
                              unsigned short* __restrict__ Qb, unsigned short* __restrict__ Kb) {
    const float scale = 0.04419417382415922f;  // 1/sqrt(512)
    size_t i = ((size_t)blockIdx.x * 256 + threadIdx.x) * 4;
    float4 q = *(const float4*)(Q + i);
    float4 k = *(const float4*)(K + i);
    ushort4 qo, ko;
    qo.x = f2bf(q.x * scale); qo.y = f2bf(q.y * scale);
    qo.z = f2bf(q.z * scale); qo.w = f2bf(q.w * scale);
    ko.x = f2bf(k.x); ko.y = f2bf(k.y); ko.z = f2bf(k.z); ko.w = f2bf(k.w);
    *(ushort4*)(Qb + i) = qo;
    *(ushort4*)(Kb + i) = ko;
}

// ---- pre-pass: V fp32 [b][s][d] -> V^T bf16 [b][d][s] ----
__global__ void cvt_vt_kernel(const float* __restrict__ V, unsigned short* __restrict__ Vt) {
    __shared__ float tile[32][33];
    int bid = blockIdx.x;
    int dt = bid & 15;          // D/32 = 16
    int st = (bid >> 4) & 63;   // S/32 = 64
    int b  = bid >> 10;
    int t = threadIdx.x;
    int sl = t >> 3, dq = t & 7;
    const float* src = V + ((size_t)b * NS + st * 32 + sl) * ND + dt * 32 + dq * 4;
    float4 v = *(const float4*)src;
    tile[sl][dq * 4 + 0] = v.x; tile[sl][dq * 4 + 1] = v.y;
    tile[sl][dq * 4 + 2] = v.z; tile[sl][dq * 4 + 3] = v.w;
    __syncthreads();
    int dl = t >> 3, sq = t & 7;
    ushort4 o;
    o.x = f2bf(tile[sq * 4 + 0][dl]);
    o.y = f2bf(tile[sq * 4 + 1][dl]);
    o.z = f2bf(tile[sq * 4 + 2][dl]);
    o.w = f2bf(tile[sq * 4 + 3][dl]);
    *(ushort4*)(Vt + ((size_t)b * ND + dt * 32 + dl) * NS + st * 32 + sq * 4) = o;
}

// ---- main flash-attention kernel ----
// grid: NB*(NS/QB)=512 blocks; 512 threads (8 waves). b = blockIdx&7 (XCD affinity).
// K and V^T are read DIRECTLY from global (L2-resident: 2MB each per batch).
// QK^T: wave w owns k-cols [w*16, w*16+16) of the KB=128 tile (no duplicate loads).
// PV:   wave w owns output d-cols [w*64, w*64+64)  -> O acc = 32 VGPR.
__global__ void __launch_bounds__(512, 4) attn_kernel(const unsigned short* __restrict__ Qg_,
                                                      const unsigned short* __restrict__ Kg_,
                                                      const unsigned short* __restrict__ Vg_,
                                                      float* __restrict__ out) {
    __shared__ __align__(16) char smem[LDS_BYTES];
    unsigned short* Qs  = (unsigned short*)(smem + QS_OFF);   // [32][QP]
    unsigned short* Ps  = (unsigned short*)(smem + PS_OFF);   // [32][PP]
    float* mrow = (float*)(smem + MROW_OFF);                  // [32]
    float* arow = (float*)(smem + AROW_OFF);                  // [32]
    float* lrow = (float*)(smem + LROW_OFF);                  // [32]
    float* tmax = (float*)(smem + TMAX_OFF);                  // [8][32]
    float* tsum = (float*)(smem + TSUM_OFF);                  // [8][32]

    const int tid  = threadIdx.x;
    const int lane = tid & 63;
    const int w    = tid >> 6;     // 0..7
    const int g    = lane >> 4;    // 0..3
    const int c    = lane & 15;    // 0..15
    const int b    = blockIdx.x & 7;
    const int qt   = blockIdx.x >> 3;

    const unsigned short* Qg = Qg_ + ((size_t)b * NS + qt * QB) * ND;
    const unsigned short* Kg = Kg_ + (size_t)b * NS * ND;
    const unsigned short* Vg = Vg_ + (size_t)b * ND * NS;   // [512][2048]

    // stage Q tile (32 x 512 bf16)
    #pragma unroll
    for (int it = 0; it < 4; ++it) {
        int idx = it * 4096 + tid * 8;
        int r = idx >> 9, cc = idx & 511;
        *(s16x8*)(Qs + r * QP + cc) = *(const s16x8*)(Qg + idx);
    }
    if (tid < 32) { mrow[tid] = -INFINITY; lrow[tid] = 0.f; }
    __syncthreads();

    f32x4 o[2][4];
    #pragma unroll
    for (int i = 0; i < 2; ++i)
        for (int j = 0; j < 4; ++j) o[i][j] = (f32x4){0.f, 0.f, 0.f, 0.f};

    for (int kt = 0; kt < NS / KB; ++kt) {
        // ---- QK^T: 32q x 16k per wave, K fragments direct from global ----
        f32x4 sc[2] = {(f32x4){0.f,0.f,0.f,0.f}, (f32x4){0.f,0.f,0.f,0.f}};
        {
            const unsigned short* Kp = Kg + (size_t)(kt * KB + w * 16 + c) * ND + g * 8;
            s16x8 kf[2][4];
            #pragma unroll
            for (int dd = 0; dd < 4; ++dd) kf[0][dd] = *(const s16x8*)(Kp + dd * 32);
            #pragma unroll
            for (int dc = 0; dc < 4; ++dc) {
                const int cur = dc & 1, nxt = cur ^ 1;
                if (dc < 3) {
                    #pragma unroll
                    for (int dd = 0; dd < 4; ++dd)
                        kf[nxt][dd] = *(const s16x8*)(Kp + (dc + 1) * 128 + dd * 32);
                }
                #pragma unroll
                for (int dd = 0; dd < 4; ++dd) {
                    const int ds = dc * 4 + dd;
                    #pragma unroll
                    for (int qb = 0; qb < 2; ++qb) {
                        s16x8 aq = *(const s16x8*)(Qs + (qb * 16 + c) * QP + ds * 32 + g * 8);
                        sc[qb] = __builtin_amdgcn_mfma_f32_16x16x32_bf16(aq, kf[cur][dd], sc[qb], 0, 0, 0);
                    }
                }
            }
        }

        // ---- online softmax ----
        f32x4 rm[2] = {sc[0], sc[1]};
        #pragma unroll
        for (int off = 1; off < 16; off <<= 1)
            #pragma unroll
            for (int qb = 0; qb < 2; ++qb)
                for (int r = 0; r < 4; ++r)
                    rm[qb][r] = fmaxf(rm[qb][r], __shfl_xor(rm[qb][r], off));
        if (c == 0)
            #pragma unroll
            for (int qb = 0; qb < 2; ++qb)
                for (int r = 0; r < 4; ++r)
                    tmax[w * 32 + qb * 16 + g * 4 + r] = rm[qb][r];
        __syncthreads();                                     // B1
        if (tid < 32) {
            float mo = mrow[tid];
            float mn = mo;
            #pragma unroll
            for (int ww = 0; ww < 8; ++ww) mn = fmaxf(mn, tmax[ww * 32 + tid]);
            mrow[tid] = mn;
            arow[tid] = __expf(mo - mn);   // 0 on first tile
        }
        __syncthreads();                                     // B2

        float mn8[2][4], a8[2][4];
        #pragma unroll
        for (int qb = 0; qb < 2; ++qb)
            for (int r = 0; r < 4; ++r) {
                int row = qb * 16 + g * 4 + r;
                mn8[qb][r] = mrow[row];
                a8[qb][r]  = arow[row];
            }
        f32x4 p[2];
        #pragma unroll
        for (int qb = 0; qb < 2; ++qb)
            for (int r = 0; r < 4; ++r)
                p[qb][r] = __expf(sc[qb][r] - mn8[qb][r]);
        #pragma unroll
        for (int qb = 0; qb < 2; ++qb)
            for (int nb = 0; nb < 4; ++nb)
                for (int r = 0; r < 4; ++r)
                    o[qb][nb][r] *= a8[qb][r];
        f32x4 rs[2] = {p[0], p[1]};
        #pragma unroll
        for (int off = 1; off < 16; off <<= 1)
            #pragma unroll
            for (int qb = 0; qb < 2; ++qb)
                for (int r = 0; r < 4; ++r)
                    rs[qb][r] += __shfl_xor(rs[qb][r], off);
        if (c == 0)
            #pragma unroll
            for (int qb = 0; qb < 2; ++qb)
                for (int r = 0; r < 4; ++r)
                    tsum[w * 32 + qb * 16 + g * 4 + r] = rs[qb][r];
        #pragma unroll
        for (int qb = 0; qb < 2; ++qb)
            for (int r = 0; r < 4; ++r)
                Ps[(qb * 16 + g * 4 + r) * PP + w * 16 + c] = f2bf(p[qb][r]);
        __syncthreads();                                     // B3
        if (tid < 32) {
            float s = 0.f;
            #pragma unroll
            for (int ww = 0; ww < 8; ++ww) s += tsum[ww * 32 + tid];
            lrow[tid] = lrow[tid] * arow[tid] + s;
        }

        // ---- PV: O[32 x 64(w)] += P(32x128) @ V(128x64), V^T direct from global ----
        {
            s16x8 ap[2][4];
            #pragma unroll
            for (int qb = 0; qb < 2; ++qb)
                for (int ks = 0; ks < 4; ++ks)
                    ap[qb][ks] = *(const s16x8*)(Ps + (qb * 16 + c) * PP + ks * 32 + g * 8);
            const unsigned short* Vp = Vg + (size_t)(w * 64 + c) * NS + kt * KB + g * 8;
            s16x8 vf[2][2];
            #pragma unroll
            for (int kp = 0; kp < 2; ++kp) vf[0][kp] = *(const s16x8*)(Vp + kp * 32);
            #pragma unroll
            for (int st = 0; st < 8; ++st) {   // st = nb*2 + kh
                const int nb = st >> 1, kh = st & 1;
                const int cur = st & 1 ? 1 : 0, nxt = cur ^ 1;
                if (st < 7) {
                    const int nb2 = (st + 1) >> 1, kh2 = (st + 1) & 1;
                    #pragma unroll
                    for (int kp = 0; kp < 2; ++kp)
                        vf[nxt][kp] = *(const s16x8*)(Vp + (size_t)nb2 * 16 * NS + (kh2 * 2 + kp) * 32);
                }
                #pragma unroll
                for (int kp = 0; kp < 2; ++kp)
                    #pragma unroll
                    for (int qb = 0; qb < 2; ++qb)
                        o[qb][nb] = __builtin_amdgcn_mfma_f32_16x16x32_bf16(
                            ap[qb][kh * 2 + kp], vf[cur][kp], o[qb][nb], 0, 0, 0);
            }
        }
    }

    __syncthreads();
    float li[2][4];
    #pragma unroll
    for (int qb = 0; qb < 2; ++qb)
        for (int r = 0; r < 4; ++r)
            li[qb][r] = 1.f / lrow[qb * 16 + g * 4 + r];
    float* Og = out + ((size_t)b * NS + qt * QB) * ND;
    #pragma unroll
    for (int qb = 0; qb < 2; ++qb)
        for (int nb = 0; nb < 4; ++nb)
            for (int r = 0; r < 4; ++r)
                Og[(size_t)(qb * 16 + g * 4 + r) * ND + w * 64 + nb * 16 + c] =
                    o[qb][nb][r] * li[qb][r];
}

extern "C" void kernel_launch(void* const* d_in, const int* in_sizes, int n_in,
                              void* d_out, int out_size, void* d_ws, size_t ws_size,
                              hipStream_t stream) {
    const float* V = (const float*)d_in[0];
    const float* K = (const float*)d_in[1];
    const float* Q = (const float*)d_in[2];
    float* out = (float*)d_out;

    unsigned short* Qb = (unsigned short*)d_ws;
    unsigned short* Kb = Qb + (size_t)NB * NS * ND;
    unsigned short* Vt = Kb + (size_t)NB * NS * ND;

    cvt_qk_kernel<<<8192, 256, 0, stream>>>(Q, K, Qb, Kb);
    cvt_vt_kernel<<<8192, 256, 0, stream>>>(V, Vt);
    attn_kernel<<<NB * (NS / QB), 512, 0, stream>>>(Qb, Kb, Vt, out);
}

// Round 3
// 177.295 us; speedup vs baseline: 3.4331x; 1.5166x over previous
//
#include <hip/hip_runtime.h>

#define NB 8
#define NS 2048
#define ND 512
#define QB 64
#define KB 128

#define QP 520   // Q LDS pitch (bf16): 512 + 8
#define PP 136   // P tile pitch: 128 + 8

// LDS offsets (bytes)
#define QS_OFF   0        // 64*520*2 = 66560
#define PS_OFF   66560    // 64*136*2 = 17408
#define TMAX_OFF 83968    // 64*8*4  = 2048
#define TSUM_OFF 86016    // 2048
#define MROW_OFF 88064    // 2*64*4  = 512
#define AROW_OFF 88576    // 64*4 -> pad 512
#define LROW_OFF 89088    // 64*4 -> pad 512
#define LDS_BYTES 89600

typedef __attribute__((ext_vector_type(4))) float f32x4;
typedef __attribute__((ext_vector_type(8))) short s16x8;

__device__ __forceinline__ unsigned short f2bf(float f) {
    unsigned int u = __float_as_uint(f);
    u += 0x7FFF + ((u >> 16) & 1);   // round-to-nearest-even
    return (unsigned short)(u >> 16);
}

// ---- pre-pass: Q,K fp32 -> bf16 (Q pre-scaled by 1/sqrt(D)) ----
__global__ void cvt_qk_kernel(const float* __restrict__ Q, const float* __restrict__ K,
                              unsigned short* __restrict__ Qb, unsigned short* __restrict__ Kb) {
    const float scale = 0.04419417382415922f;  // 1/sqrt(512)
    size_t i = ((size_t)blockIdx.x * 256 + threadIdx.x) * 4;
    float4 q = *(const float4*)(Q + i);
    float4 k = *(const float4*)(K + i);
    ushort4 qo, ko;
    qo.x = f2bf(q.x * scale); qo.y = f2bf(q.y * scale);
    qo.z = f2bf(q.z * scale); qo.w = f2bf(q.w * scale);
    ko.x = f2bf(k.x); ko.y = f2bf(k.y); ko.z = f2bf(k.z); ko.w = f2bf(k.w);
    *(ushort4*)(Qb + i) = qo;
    *(ushort4*)(Kb + i) = ko;
}

// ---- pre-pass: V fp32 [b][s][d] -> V^T bf16 [b][d][s] ----
__global__ void cvt_vt_kernel(const float* __restrict__ V, unsigned short* __restrict__ Vt) {
    __shared__ float tile[32][33];
    int bid = blockIdx.x;
    int dt = bid & 15;          // D/32 = 16
    int st = (bid >> 4) & 63;   // S/32 = 64
    int b  = bid >> 10;
    int t = threadIdx.x;
    int sl = t >> 3, dq = t & 7;
    const float* src = V + ((size_t)b * NS + st * 32 + sl) * ND + dt * 32 + dq * 4;
    float4 v = *(const float4*)src;
    tile[sl][dq * 4 + 0] = v.x; tile[sl][dq * 4 + 1] = v.y;
    tile[sl][dq * 4 + 2] = v.z; tile[sl][dq * 4 + 3] = v.w;
    __syncthreads();
    int dl = t >> 3, sq = t & 7;
    ushort4 o;
    o.x = f2bf(tile[sq * 4 + 0][dl]);
    o.y = f2bf(tile[sq * 4 + 1][dl]);
    o.z = f2bf(tile[sq * 4 + 2][dl]);
    o.w = f2bf(tile[sq * 4 + 3][dl]);
    *(ushort4*)(Vt + ((size_t)b * ND + dt * 32 + dl) * NS + st * 32 + sq * 4) = o;
}

// ---- main flash-attention kernel ----
// grid 256 = NB * (NS/QB); 512 threads (8 waves); b = blockIdx&7 -> XCD b holds batch b's K+V (4MB = L2).
// QK^T (swapped, A=K B=Q): wave w owns k-cols [w*16,w*16+16); lane holds S[k][q] -> k-reduce is in-reg + 2 shfl.
// PV: wave w owns output d-cols [w*64, w*64+64).
__global__ void __launch_bounds__(512, 2) attn_kernel(const unsigned short* __restrict__ Qg_,
                                                      const unsigned short* __restrict__ Kg_,
                                                      const unsigned short* __restrict__ Vg_,
                                                      float* __restrict__ out) {
    extern __shared__ __align__(16) char smem[];
    unsigned short* Qs = (unsigned short*)(smem + QS_OFF);   // [64][QP]
    unsigned short* Ps = (unsigned short*)(smem + PS_OFF);   // [64][PP]
    float* tmax = (float*)(smem + TMAX_OFF);                 // [64][8]
    float* tsum = (float*)(smem + TSUM_OFF);                 // [64][8]
    float* mrow = (float*)(smem + MROW_OFF);                 // [2][64]
    float* arow = (float*)(smem + AROW_OFF);                 // [64]
    float* lrow = (float*)(smem + LROW_OFF);                 // [64]

    const int tid  = threadIdx.x;
    const int lane = tid & 63;
    const int w    = tid >> 6;     // 0..7
    const int g    = lane >> 4;    // 0..3
    const int c    = lane & 15;    // 0..15
    const int b    = blockIdx.x & 7;
    const int qt   = blockIdx.x >> 3;

    const unsigned short* Qg = Qg_ + ((size_t)b * NS + qt * QB) * ND;
    const unsigned short* Kg = Kg_ + (size_t)b * NS * ND;
    const unsigned short* Vg = Vg_ + (size_t)b * ND * NS;   // [512][2048]

    // stage Q tile (64 x 512 bf16)
    #pragma unroll
    for (int it = 0; it < 8; ++it) {
        int idx = it * 4096 + tid * 8;
        int r = idx >> 9, cc = idx & 511;
        *(s16x8*)(Qs + r * QP + cc) = *(const s16x8*)(Qg + idx);
    }
    if (tid < 64) { mrow[tid] = -INFINITY; lrow[tid] = 0.f; }
    __syncthreads();

    f32x4 o[4][4];
    #pragma unroll
    for (int i = 0; i < 4; ++i)
        for (int j = 0; j < 4; ++j) o[i][j] = (f32x4){0.f, 0.f, 0.f, 0.f};

    const unsigned short* Kp = Kg + (size_t)(w * 16 + c) * ND + g * 8;
    const unsigned short* Vp = Vg + (size_t)(w * 64 + c) * NS + g * 8;

    s16x8 kf[2][4];
    #pragma unroll
    for (int dd = 0; dd < 4; ++dd) kf[0][dd] = *(const s16x8*)(Kp + dd * 32);

    for (int kt = 0; kt < NS / KB; ++kt) {
        const unsigned short* Kcur = Kp + (size_t)kt * KB * ND;
        // ---- QK^T (swapped): sc[qb] = S[k = w*16+g*4+r][q = qb*16+c] ----
        f32x4 sc[4];
        #pragma unroll
        for (int qb = 0; qb < 4; ++qb) sc[qb] = (f32x4){0.f, 0.f, 0.f, 0.f};
        #pragma unroll
        for (int dc = 0; dc < 4; ++dc) {
            const int cur = dc & 1;
            if (dc < 3) {
                #pragma unroll
                for (int dd = 0; dd < 4; ++dd)
                    kf[cur ^ 1][dd] = *(const s16x8*)(Kcur + (dc + 1) * 128 + dd * 32);
            } else if (kt < NS / KB - 1) {
                #pragma unroll
                for (int dd = 0; dd < 4; ++dd)
                    kf[cur ^ 1][dd] = *(const s16x8*)(Kcur + (size_t)KB * ND + dd * 32);
            }
            #pragma unroll
            for (int dd = 0; dd < 4; ++dd) {
                #pragma unroll
                for (int qb = 0; qb < 4; ++qb) {
                    s16x8 aq = *(const s16x8*)(Qs + (qb * 16 + c) * QP + dc * 128 + dd * 32 + g * 8);
                    sc[qb] = __builtin_amdgcn_mfma_f32_16x16x32_bf16(kf[cur][dd], aq, sc[qb], 0, 0, 0);
                }
            }
        }

        // issue V loads for ks=0 early (hide under softmax)
        s16x8 bv[2][4];
        #pragma unroll
        for (int nb = 0; nb < 4; ++nb)
            bv[0][nb] = *(const s16x8*)(Vp + (size_t)nb * 16 * NS + kt * KB);

        // ---- wave-local per-q max over this wave's 16 k values ----
        #pragma unroll
        for (int qb = 0; qb < 4; ++qb) {
            float m4 = fmaxf(fmaxf(sc[qb][0], sc[qb][1]), fmaxf(sc[qb][2], sc[qb][3]));
            m4 = fmaxf(m4, __shfl_xor(m4, 16));
            m4 = fmaxf(m4, __shfl_xor(m4, 32));
            if (lane < 16) tmax[(qb * 16 + c) * 8 + w] = m4;
        }
        __syncthreads();                                     // B1: tmax ready
        const int par = kt & 1;
        {   // cooperative max/alpha pass (8 dup threads per row write same value)
            int row = tid & 63;
            f32x4 t0 = *(const f32x4*)(tmax + row * 8);
            f32x4 t1 = *(const f32x4*)(tmax + row * 8 + 4);
            float mx = fmaxf(fmaxf(fmaxf(t0[0], t0[1]), fmaxf(t0[2], t0[3])),
                             fmaxf(fmaxf(t1[0], t1[1]), fmaxf(t1[2], t1[3])));
            float mo = mrow[par * 64 + row];
            float mn = fmaxf(mo, mx);
            mrow[(par ^ 1) * 64 + row] = mn;
            arow[row] = __expf(mo - mn);                     // 0 on first tile
        }
        __syncthreads();                                     // B1b: mrow/arow ready

        // ---- P = exp(S - m), row sums, P -> LDS (packed) ----
        #pragma unroll
        for (int qb = 0; qb < 4; ++qb) {
            float mq = mrow[(par ^ 1) * 64 + qb * 16 + c];
            #pragma unroll
            for (int r = 0; r < 4; ++r) sc[qb][r] = __expf(sc[qb][r] - mq);
            float s4 = (sc[qb][0] + sc[qb][1]) + (sc[qb][2] + sc[qb][3]);
            s4 += __shfl_xor(s4, 16);
            s4 += __shfl_xor(s4, 32);
            if (lane < 16) tsum[(qb * 16 + c) * 8 + w] = s4;
            ushort4 pk;
            pk.x = f2bf(sc[qb][0]); pk.y = f2bf(sc[qb][1]);
            pk.z = f2bf(sc[qb][2]); pk.w = f2bf(sc[qb][3]);
            *(ushort4*)(Ps + (qb * 16 + c) * PP + w * 16 + g * 4) = pk;
        }
        // rescale O by alpha (broadcast LDS reads)
        #pragma unroll
        for (int qb = 0; qb < 4; ++qb)
            #pragma unroll
            for (int r = 0; r < 4; ++r) {
                float al = arow[qb * 16 + g * 4 + r];
                #pragma unroll
                for (int nb = 0; nb < 4; ++nb) o[qb][nb][r] *= al;
            }
        __syncthreads();                                     // B2: Ps + tsum ready
        if (tid < 64) {   // single-writer l update (wave 0)
            int row = tid;
            f32x4 s0 = *(const f32x4*)(tsum + row * 8);
            f32x4 s1 = *(const f32x4*)(tsum + row * 8 + 4);
            float ls = (s0[0] + s0[1] + s0[2] + s0[3]) + (s1[0] + s1[1] + s1[2] + s1[3]);
            lrow[row] = lrow[row] * arow[row] + ls;
        }

        // ---- PV: O[64 x 64(w)] += P(64x128) @ V(128x64) ----
        #pragma unroll
        for (int ks = 0; ks < 4; ++ks) {
            const int cur = ks & 1;
            if (ks < 3) {
                #pragma unroll
                for (int nb = 0; nb < 4; ++nb)
                    bv[cur ^ 1][nb] = *(const s16x8*)(Vp + (size_t)nb * 16 * NS + kt * KB + (ks + 1) * 32);
            }
            #pragma unroll
            for (int qb = 0; qb < 4; ++qb) {
                s16x8 ap = *(const s16x8*)(Ps + (qb * 16 + c) * PP + ks * 32 + g * 8);
                #pragma unroll
                for (int nb = 0; nb < 4; ++nb)
                    o[qb][nb] = __builtin_amdgcn_mfma_f32_16x16x32_bf16(ap, bv[cur][nb], o[qb][nb], 0, 0, 0);
            }
        }
    }

    __syncthreads();
    float* Og = out + ((size_t)b * NS + qt * QB) * ND;
    #pragma unroll
    for (int qb = 0; qb < 4; ++qb)
        #pragma unroll
        for (int r = 0; r < 4; ++r) {
            float li = 1.f / lrow[qb * 16 + g * 4 + r];
            #pragma unroll
            for (int nb = 0; nb < 4; ++nb)
                Og[(size_t)(qb * 16 + g * 4 + r) * ND + w * 64 + nb * 16 + c] =
                    o[qb][nb][r] * li;
        }
}

extern "C" void kernel_launch(void* const* d_in, const int* in_sizes, int n_in,
                              void* d_out, int out_size, void* d_ws, size_t ws_size,
                              hipStream_t stream) {
    const float* V = (const float*)d_in[0];
    const float* K = (const float*)d_in[1];
    const float* Q = (const float*)d_in[2];
    float* out = (float*)d_out;

    unsigned short* Qb = (unsigned short*)d_ws;
    unsigned short* Kb = Qb + (size_t)NB * NS * ND;
    unsigned short* Vt = Kb + (size_t)NB * NS * ND;

    hipFuncSetAttribute(reinterpret_cast<const void*>(attn_kernel),
                        hipFuncAttributeMaxDynamicSharedMemorySize, LDS_BYTES);

    cvt_qk_kernel<<<8192, 256, 0, stream>>>(Q, K, Qb, Kb);
    cvt_vt_kernel<<<8192, 256, 0, stream>>>(V, Vt);
    attn_kernel<<<NB * (NS / QB), 512, LDS_BYTES, stream>>>(Qb, Kb, Vt, out);
}

// Round 4
// 157.059 us; speedup vs baseline: 3.8755x; 1.1288x over previous
//
#include <hip/hip_runtime.h>

#define NB 8
#define NS 2048
#define ND 512
#define QB 64
#define KB 256

// LDS offsets (bytes); Qs/Ps are XOR-swizzled (T2), no padding
#define QS_OFF   0         // 64*512*2 = 65536
#define PS_OFF   65536     // 64*256*2 = 32768
#define TMAX_OFF 98304     // 64*12*4  = 3072
#define TSUM_OFF 101376    // 3072
#define MROW_OFF 104448    // 2*64*4   = 512
#define AROW_OFF 104960    // 256
#define LROW_OFF 105216    // 256
#define LDS_BYTES 105472

typedef __attribute__((ext_vector_type(4)))  float f32x4;
typedef __attribute__((ext_vector_type(16))) float f32x16;
typedef __attribute__((ext_vector_type(8)))  short s16x8;

__device__ __forceinline__ unsigned short f2bf(float f) {
    unsigned int u = __float_as_uint(f);
    u += 0x7FFF + ((u >> 16) & 1);
    return (unsigned short)(u >> 16);
}

// ---- pre-pass: Q,K fp32 -> bf16 (Q pre-scaled by 1/sqrt(D)) ----
__global__ void cvt_qk_kernel(const float* __restrict__ Q, const float* __restrict__ K,
                              unsigned short* __restrict__ Qb, unsigned short* __restrict__ Kb) {
    const float scale = 0.04419417382415922f;
    size_t i = ((size_t)blockIdx.x * 256 + threadIdx.x) * 4;
    float4 q = *(const float4*)(Q + i);
    float4 k = *(const float4*)(K + i);
    ushort4 qo, ko;
    qo.x = f2bf(q.x * scale); qo.y = f2bf(q.y * scale);
    qo.z = f2bf(q.z * scale); qo.w = f2bf(q.w * scale);
    ko.x = f2bf(k.x); ko.y = f2bf(k.y); ko.z = f2bf(k.z); ko.w = f2bf(k.w);
    *(ushort4*)(Qb + i) = qo;
    *(ushort4*)(Kb + i) = ko;
}

// ---- pre-pass: V fp32 [b][s][d] -> V^T bf16 [b][d][s] ----
__global__ void cvt_vt_kernel(const float* __restrict__ V, unsigned short* __restrict__ Vt) {
    __shared__ float tile[32][33];
    int bid = blockIdx.x;
    int dt = bid & 15;
    int st = (bid >> 4) & 63;
    int b  = bid >> 10;
    int t = threadIdx.x;
    int sl = t >> 3, dq = t & 7;
    const float* src = V + ((size_t)b * NS + st * 32 + sl) * ND + dt * 32 + dq * 4;
    float4 v = *(const float4*)src;
    tile[sl][dq * 4 + 0] = v.x; tile[sl][dq * 4 + 1] = v.y;
    tile[sl][dq * 4 + 2] = v.z; tile[sl][dq * 4 + 3] = v.w;
    __syncthreads();
    int dl = t >> 3, sq = t & 7;
    ushort4 o;
    o.x = f2bf(tile[sq * 4 + 0][dl]);
    o.y = f2bf(tile[sq * 4 + 1][dl]);
    o.z = f2bf(tile[sq * 4 + 2][dl]);
    o.w = f2bf(tile[sq * 4 + 3][dl]);
    *(ushort4*)(Vt + ((size_t)b * ND + dt * 32 + dl) * NS + st * 32 + sq * 4) = o;
}

// ---- main flash-attention kernel ----
// grid 256; 512 threads (8 waves); b = blockIdx&7 (XCD affinity: batch's K+V = 4MB = one L2).
// QK^T swapped (A=K,B=Q) in 32x32x16: wave w owns k-rows [w*32, w*32+32) of the KB=256 tile.
// PV in 16x16x32: wave w owns output d-cols [w*64, w*64+64).
__global__ void __launch_bounds__(512, 2) attn_kernel(const unsigned short* __restrict__ Qg_,
                                                      const unsigned short* __restrict__ Kg_,
                                                      const unsigned short* __restrict__ Vg_,
                                                      float* __restrict__ out) {
    extern __shared__ __align__(16) char smem[];
    unsigned short* Qs = (unsigned short*)(smem + QS_OFF);   // [64][512] swizzled
    unsigned short* Ps = (unsigned short*)(smem + PS_OFF);   // [64][256] swizzled
    float* tmax = (float*)(smem + TMAX_OFF);                 // [64][12]
    float* tsum = (float*)(smem + TSUM_OFF);                 // [64][12]
    float* mrow = (float*)(smem + MROW_OFF);                 // [2][64]
    float* arow = (float*)(smem + AROW_OFF);                 // [64]
    float* lrow = (float*)(smem + LROW_OFF);                 // [64]

    const int tid  = threadIdx.x;
    const int lane = tid & 63;
    const int w    = tid >> 6;     // 0..7
    const int hi   = lane >> 5;    // 0/1
    const int l31  = lane & 31;
    const int g    = lane >> 4;    // 0..3 (PV)
    const int c    = lane & 15;    // 0..15 (PV)
    const int b    = blockIdx.x & 7;
    const int qt   = blockIdx.x >> 3;

    const unsigned short* Qg = Qg_ + ((size_t)b * NS + qt * QB) * ND;
    const unsigned short* Kg = Kg_ + (size_t)b * NS * ND;
    const unsigned short* Vg = Vg_ + (size_t)b * ND * NS;   // [512][2048]

    // stage Q tile (64 x 512), swizzled: col ^= (row&7)<<3 (shorts)
    #pragma unroll
    for (int it = 0; it < 8; ++it) {
        int idx = it * 4096 + tid * 8;
        int r = idx >> 9, cc = idx & 511;
        *(s16x8*)(Qs + r * 512 + (cc ^ ((r & 7) << 3))) = *(const s16x8*)(Qg + idx);
    }
    if (tid < 64) { mrow[tid] = -INFINITY; lrow[tid] = 0.f; }
    __syncthreads();

    f32x4 o[4][4];
    #pragma unroll
    for (int i = 0; i < 4; ++i)
        for (int j = 0; j < 4; ++j) o[i][j] = (f32x4){0.f, 0.f, 0.f, 0.f};

    // K A-frag base: row = w*32 + l31, d-offset hi*8
    const unsigned short* Kp = Kg + (size_t)(w * 32 + l31) * ND + hi * 8;
    // V B-frag base: d-row = w*64 + c, k-offset g*8
    const unsigned short* Vp = Vg + (size_t)(w * 64 + c) * NS + g * 8;
    // Q B-frag swizzle: col ^ ((l31&7)<<3), rows qb*32 + l31
    const int qsw = (l31 & 7) << 3;

    // 8-deep K fragment ring (covers L2 latency; crosses tile boundary)
    s16x8 kr[8];
    #pragma unroll
    for (int p = 0; p < 8; ++p) kr[p] = *(const s16x8*)(Kp + p * 16);

    for (int kt = 0; kt < NS / KB; ++kt) {
        const unsigned short* Kcur = Kp + (size_t)kt * KB * ND;
        // ---- QK^T: sc[qb] = S[k = w*32 + rowmap][q = qb*32 + l31] ----
        f32x16 sc[2];
        sc[0] = (f32x16)0.f; sc[1] = (f32x16)0.f;
        #pragma unroll
        for (int s = 0; s < 32; ++s) {
            const int rg = s & 7;
            __builtin_amdgcn_s_setprio(1);
            #pragma unroll
            for (int qb = 0; qb < 2; ++qb) {
                s16x8 qf = *(const s16x8*)(Qs + (qb * 32 + l31) * 512 + ((s * 16 + hi * 8) ^ qsw));
                sc[qb] = __builtin_amdgcn_mfma_f32_32x32x16_bf16(kr[rg], qf, sc[qb], 0, 0, 0);
            }
            __builtin_amdgcn_s_setprio(0);
            if (s < 24)
                kr[rg] = *(const s16x8*)(Kcur + (s + 8) * 16);
            else if (kt < NS / KB - 1)
                kr[rg] = *(const s16x8*)(Kcur + (size_t)KB * ND + (s - 24) * 16);
        }

        // issue V ks=0,1 early (hide under softmax)
        s16x8 bv[2][4];
        #pragma unroll
        for (int ks = 0; ks < 2; ++ks)
            #pragma unroll
            for (int nb = 0; nb < 4; ++nb)
                bv[ks][nb] = *(const s16x8*)(Vp + (size_t)nb * 16 * NS + kt * KB + ks * 32);

        // ---- wave-local per-q max over wave's 32 k ----
        #pragma unroll
        for (int qb = 0; qb < 2; ++qb) {
            float m0 = sc[qb][0];
            #pragma unroll
            for (int r = 1; r < 16; ++r) m0 = fmaxf(m0, sc[qb][r]);
            m0 = fmaxf(m0, __shfl_xor(m0, 32));
            if (lane < 32) tmax[(qb * 32 + l31) * 12 + w] = m0;
        }
        __syncthreads();                                     // B1
        const int par = kt & 1;
        {   // cooperative max/alpha (8 dup writers per row, same value)
            int row = tid & 63;
            f32x4 t0 = *(const f32x4*)(tmax + row * 12);
            f32x4 t1 = *(const f32x4*)(tmax + row * 12 + 4);
            float mx = fmaxf(fmaxf(fmaxf(t0[0], t0[1]), fmaxf(t0[2], t0[3])),
                             fmaxf(fmaxf(t1[0], t1[1]), fmaxf(t1[2], t1[3])));
            float mo = mrow[par * 64 + row];
            float mn = fmaxf(mo, mx);
            mrow[(par ^ 1) * 64 + row] = mn;
            arow[row] = __expf(mo - mn);
        }
        __syncthreads();                                     // B2

        // ---- P = exp(S-m), row sums, P -> LDS packed+swizzled ----
        #pragma unroll
        for (int qb = 0; qb < 2; ++qb) {
            const int q = qb * 32 + l31;
            float mq = mrow[(par ^ 1) * 64 + q];
            #pragma unroll
            for (int r = 0; r < 16; ++r) sc[qb][r] = __expf(sc[qb][r] - mq);
            float s0 = 0.f;
            #pragma unroll
            for (int r = 0; r < 16; ++r) s0 += sc[qb][r];
            s0 += __shfl_xor(s0, 32);
            if (lane < 32) tsum[q * 12 + w] = s0;
            const int psw = (q & 7) << 3;
            #pragma unroll
            for (int rg = 0; rg < 4; ++rg) {   // regs rg*4.. -> k = w*32 + rg*8 + hi*4 + 0..3
                ushort4 pk;
                pk.x = f2bf(sc[qb][rg * 4 + 0]); pk.y = f2bf(sc[qb][rg * 4 + 1]);
                pk.z = f2bf(sc[qb][rg * 4 + 2]); pk.w = f2bf(sc[qb][rg * 4 + 3]);
                *(ushort4*)(Ps + q * 256 + ((w * 32 + rg * 8 + hi * 4) ^ psw)) = pk;
            }
        }
        // rescale O by alpha
        #pragma unroll
        for (int qb = 0; qb < 4; ++qb)
            #pragma unroll
            for (int r = 0; r < 4; ++r) {
                float al = arow[qb * 16 + g * 4 + r];
                #pragma unroll
                for (int nb = 0; nb < 4; ++nb) o[qb][nb][r] *= al;
            }
        __syncthreads();                                     // B3
        if (tid < 64) {
            int row = tid;
            f32x4 s0 = *(const f32x4*)(tsum + row * 12);
            f32x4 s1 = *(const f32x4*)(tsum + row * 12 + 4);
            float ls = (s0[0] + s0[1] + s0[2] + s0[3]) + (s1[0] + s1[1] + s1[2] + s1[3]);
            lrow[row] = lrow[row] * arow[row] + ls;
        }

        // ---- PV: O[64 x 64(w)] += P(64x256) @ V(256x64) ----
        #pragma unroll
        for (int ks = 0; ks < 8; ++ks) {
            const int sl = ks & 1;
            s16x8 ap[4];
            #pragma unroll
            for (int qb = 0; qb < 4; ++qb) {
                const int q = qb * 16 + c;
                ap[qb] = *(const s16x8*)(Ps + q * 256 + ((ks * 32 + g * 8) ^ ((q & 7) << 3)));
            }
            __builtin_amdgcn_s_setprio(1);
            #pragma unroll
            for (int qb = 0; qb < 4; ++qb)
                #pragma unroll
                for (int nb = 0; nb < 4; ++nb)
                    o[qb][nb] = __builtin_amdgcn_mfma_f32_16x16x32_bf16(ap[qb], bv[sl][nb], o[qb][nb], 0, 0, 0);
            __builtin_amdgcn_s_setprio(0);
            if (ks < 6)
                #pragma unroll
                for (int nb = 0; nb < 4; ++nb)
                    bv[sl][nb] = *(const s16x8*)(Vp + (size_t)nb * 16 * NS + kt * KB + (ks + 2) * 32);
        }
    }

    __syncthreads();
    float* Og = out + ((size_t)b * NS + qt * QB) * ND;
    #pragma unroll
    for (int qb = 0; qb < 4; ++qb)
        #pragma unroll
        for (int r = 0; r < 4; ++r) {
            float li = 1.f / lrow[qb * 16 + g * 4 + r];
            #pragma unroll
            for (int nb = 0; nb < 4; ++nb)
                Og[(size_t)(qb * 16 + g * 4 + r) * ND + w * 64 + nb * 16 + c] =
                    o[qb][nb][r] * li;
        }
}

extern "C" void kernel_launch(void* const* d_in, const int* in_sizes, int n_in,
                              void* d_out, int out_size, void* d_ws, size_t ws_size,
                              hipStream_t stream) {
    const float* V = (const float*)d_in[0];
    const float* K = (const float*)d_in[1];
    const float* Q = (const float*)d_in[2];
    float* out = (float*)d_out;

    unsigned short* Qb = (unsigned short*)d_ws;
    unsigned short* Kb = Qb + (size_t)NB * NS * ND;
    unsigned short* Vt = Kb + (size_t)NB * NS * ND;

    hipFuncSetAttribute(reinterpret_cast<const void*>(attn_kernel),
                        hipFuncAttributeMaxDynamicSharedMemorySize, LDS_BYTES);

    cvt_qk_kernel<<<8192, 256, 0, stream>>>(Q, K, Qb, Kb);
    cvt_vt_kernel<<<8192, 256, 0, stream>>>(V, Vt);
    attn_kernel<<<NB * (NS / QB), 512, LDS_BYTES, stream>>>(Qb, Kb, Vt, out);
}